// Round 6
// baseline (158.382 us; speedup 1.0000x reference)
//
#include <hip/hip_runtime.h>

#define NN 50000
#define NE 600000
#define DD 128
#define SLOTS 64   // deg ~ Poisson(12); P(deg>=64) ~ 1e-31 -> safe fixed-capacity buckets

typedef float f32x4 __attribute__((ext_vector_type(4)));
typedef short bf16x8 __attribute__((ext_vector_type(8)));

__device__ __forceinline__ ushort f2bf(float f) {           // RNE f32 -> bf16
    uint u = __float_as_uint(f);
    u = (u + 0x7FFFu + ((u >> 16) & 1u)) >> 16;
    return (ushort)u;
}
__device__ __forceinline__ float bfhi2f(uint u) { return __uint_as_float(u & 0xFFFF0000u); }
__device__ __forceinline__ float bflo2f(uint u) { return __uint_as_float(u << 16); }

// ---------------- init: cast x and weights to bf16, zero cnt/hsum ----------------

__global__ void k_init(const float4* __restrict__ x4, uint2* __restrict__ xb,
                       const float4* __restrict__ Wl4, const float4* __restrict__ W14,
                       uint2* __restrict__ wbl2, uint2* __restrict__ wb12,
                       int* __restrict__ cnt, float* __restrict__ hsum) {
    int i = blockIdx.x * blockDim.x + threadIdx.x;
    if (i < NN * 32) {
        float4 v = x4[i];
        uint2 o;
        o.x = (uint)f2bf(v.x) | ((uint)f2bf(v.y) << 16);
        o.y = (uint)f2bf(v.z) | ((uint)f2bf(v.w) << 16);
        xb[i] = o;
    }
    if (i < 4096) {   // 16384 f32 per weight
        float4 v = Wl4[i];
        uint2 o;
        o.x = (uint)f2bf(v.x) | ((uint)f2bf(v.y) << 16);
        o.y = (uint)f2bf(v.z) | ((uint)f2bf(v.w) << 16);
        wbl2[i] = o;
        v = W14[i];
        o.x = (uint)f2bf(v.x) | ((uint)f2bf(v.y) << 16);
        o.y = (uint)f2bf(v.z) | ((uint)f2bf(v.w) << 16);
        wb12[i] = o;
    }
    if (i < NN) cnt[i] = 0;
    if (i < DD) hsum[i] = 0.0f;
}

// ---------------- bucket scatter: slot[dst*64 + pos] = src (ushort) ----------------

__global__ void k_scatter(const int* __restrict__ ei, int* __restrict__ cnt, ushort* __restrict__ slot) {
    int e = blockIdx.x * blockDim.x + threadIdx.x;
    if (e < NE) {
        int dst = ei[NE + e];
        int pos = atomicAdd(&cnt[dst], 1);
        slot[(size_t)dst * SLOTS + pos] = (ushort)ei[e];
    }
}

// ---------------- fused gather + 2-layer MFMA MLP + column-sum ----------------
// Wave-tile = 16 nodes, exactly one tile per wave (grid 782x4 waves >= 3125 tiles).
// Phase 1 (gather): quarter-wave per node (lq=node-sub, lm=16B chunk). Mean row written
//   bf16 into per-wave LDS buffer myAgg, granule-XOR-swizzled: row r, granule g at
//   ushort off r*128 + ((g^(r&7))<<3).
// Phase 2 (layer1): A-frags from myAgg, B-frags 16B direct from global bf16 Wl (L1/L2-hot),
//   C re-written into myAgg (swizzled) as bf16 agg.
// Phase 3 (layer2): A-frags from myAgg, B from global W1, relu, per-feature running sum.
// MFMA 16x16x32 bf16: A[m=l&15][k=(l>>4)*8+j]; C col=l&15, row=(l>>4)*4+reg.

__global__ __launch_bounds__(256) void k_fused(const uint4* __restrict__ xb4,
                                               const int* __restrict__ cnt,
                                               const ushort* __restrict__ slot,
                                               const ushort* __restrict__ wbl,
                                               const ushort* __restrict__ wb1,
                                               const float* __restrict__ bl,
                                               const float* __restrict__ b1,
                                               float* __restrict__ hsum) {
    __shared__ ushort sAgg[4 * 2048];   // 16 KB: per-wave 16x128 bf16

    int tid = threadIdx.x;
    int wid = tid >> 6, lane = tid & 63;
    int lm = lane & 15, lq = lane >> 4;

    float blr[8], b1r[8], hacc[8];
    #pragma unroll
    for (int ct = 0; ct < 8; ++ct) {
        blr[ct] = bl[ct * 16 + lm];
        b1r[ct] = b1[ct * 16 + lm];
        hacc[ct] = 0.0f;
    }

    ushort* myAgg = &sAgg[wid * 2048];
    const int NT = NN / 16;   // 3125

    for (int wt = blockIdx.x * 4 + wid; wt < NT; wt += gridDim.x * 4) {
        int nbase = wt * 16;

        // ---- gather: 4 passes, quarter-wave per node ----
        #pragma unroll
        for (int p = 0; p < 4; ++p) {
            int node = nbase + p * 4 + lq;
            uint4 sv = xb4[(size_t)node * 16 + lm];   // self loop
            float a0 = bflo2f(sv.x), a1 = bfhi2f(sv.x), a2 = bflo2f(sv.y), a3 = bfhi2f(sv.y);
            float a4 = bflo2f(sv.z), a5 = bfhi2f(sv.z), a6 = bflo2f(sv.w), a7 = bfhi2f(sv.w);
            const ushort* sl = slot + (size_t)node * SLOTS;
            int n = cnt[node];
            int j = 0;
            for (; j + 3 < n; j += 4) {
                int s0 = sl[j], s1 = sl[j + 1], s2 = sl[j + 2], s3 = sl[j + 3];
                uint4 v0 = xb4[(size_t)s0 * 16 + lm];
                uint4 v1 = xb4[(size_t)s1 * 16 + lm];
                uint4 v2 = xb4[(size_t)s2 * 16 + lm];
                uint4 v3 = xb4[(size_t)s3 * 16 + lm];
                a0 += bflo2f(v0.x) + bflo2f(v1.x) + bflo2f(v2.x) + bflo2f(v3.x);
                a1 += bfhi2f(v0.x) + bfhi2f(v1.x) + bfhi2f(v2.x) + bfhi2f(v3.x);
                a2 += bflo2f(v0.y) + bflo2f(v1.y) + bflo2f(v2.y) + bflo2f(v3.y);
                a3 += bfhi2f(v0.y) + bfhi2f(v1.y) + bfhi2f(v2.y) + bfhi2f(v3.y);
                a4 += bflo2f(v0.z) + bflo2f(v1.z) + bflo2f(v2.z) + bflo2f(v3.z);
                a5 += bfhi2f(v0.z) + bfhi2f(v1.z) + bfhi2f(v2.z) + bfhi2f(v3.z);
                a6 += bflo2f(v0.w) + bflo2f(v1.w) + bflo2f(v2.w) + bflo2f(v3.w);
                a7 += bfhi2f(v0.w) + bfhi2f(v1.w) + bfhi2f(v2.w) + bfhi2f(v3.w);
            }
            for (; j < n; ++j) {
                uint4 v = xb4[(size_t)sl[j] * 16 + lm];
                a0 += bflo2f(v.x); a1 += bfhi2f(v.x);
                a2 += bflo2f(v.y); a3 += bfhi2f(v.y);
                a4 += bflo2f(v.z); a5 += bfhi2f(v.z);
                a6 += bflo2f(v.w); a7 += bfhi2f(v.w);
            }
            float rc = 1.0f / (float)(n + 1);
            union { ushort u[8]; bf16x8 v; } t;
            t.u[0] = f2bf(a0 * rc); t.u[1] = f2bf(a1 * rc);
            t.u[2] = f2bf(a2 * rc); t.u[3] = f2bf(a3 * rc);
            t.u[4] = f2bf(a4 * rc); t.u[5] = f2bf(a5 * rc);
            t.u[6] = f2bf(a6 * rc); t.u[7] = f2bf(a7 * rc);
            int row = p * 4 + lq;
            *(bf16x8*)&myAgg[row * 128 + ((lm ^ (row & 7)) << 3)] = t.v;
        }

        // ---- layer 1: agg = mean @ Wl^T + bl ----
        bf16x8 afr[4];
        #pragma unroll
        for (int kt = 0; kt < 4; ++kt)
            afr[kt] = *(const bf16x8*)&myAgg[lm * 128 + (((kt * 4 + lq) ^ (lm & 7)) << 3)];

        #pragma unroll
        for (int ct = 0; ct < 8; ++ct) {
            f32x4 acc = {0.f, 0.f, 0.f, 0.f};
            int rB = ct * 16 + lm;
            #pragma unroll
            for (int kt = 0; kt < 4; ++kt) {
                bf16x8 bfr = *(const bf16x8*)&wbl[rB * 128 + (kt * 4 + lq) * 8];
                acc = __builtin_amdgcn_mfma_f32_16x16x32_bf16(afr[kt], bfr, acc, 0, 0, 0);
            }
            #pragma unroll
            for (int r = 0; r < 4; ++r) {
                int n = lq * 4 + r;
                int col = ct * 16 + lm;
                myAgg[n * 128 + (((col >> 3) ^ (n & 7)) << 3) + (col & 7)] = f2bf(acc[r] + blr[ct]);
            }
        }

        // ---- layer 2: h = relu(agg @ W1^T + b1), accumulate column sums ----
        bf16x8 afr2[4];
        #pragma unroll
        for (int kt = 0; kt < 4; ++kt)
            afr2[kt] = *(const bf16x8*)&myAgg[lm * 128 + (((kt * 4 + lq) ^ (lm & 7)) << 3)];

        #pragma unroll
        for (int ct = 0; ct < 8; ++ct) {
            f32x4 acc = {0.f, 0.f, 0.f, 0.f};
            int rB = ct * 16 + lm;
            #pragma unroll
            for (int kt = 0; kt < 4; ++kt) {
                bf16x8 bfr = *(const bf16x8*)&wb1[rB * 128 + (kt * 4 + lq) * 8];
                acc = __builtin_amdgcn_mfma_f32_16x16x32_bf16(afr2[kt], bfr, acc, 0, 0, 0);
            }
            float s0 = fmaxf(acc[0] + b1r[ct], 0.f);
            float s1 = fmaxf(acc[1] + b1r[ct], 0.f);
            float s2 = fmaxf(acc[2] + b1r[ct], 0.f);
            float s3 = fmaxf(acc[3] + b1r[ct], 0.f);
            hacc[ct] += (s0 + s1) + (s2 + s3);
        }
    }

    // reduce: lanes sharing lm hold disjoint node subsets
    #pragma unroll
    for (int ct = 0; ct < 8; ++ct) {
        float v = hacc[ct];
        v += __shfl_xor(v, 16);
        v += __shfl_xor(v, 32);
        hacc[ct] = v;
    }
    __syncthreads();
    float* red = (float*)sAgg;
    if (lane < 16) {
        #pragma unroll
        for (int ct = 0; ct < 8; ++ct) red[wid * 128 + ct * 16 + lane] = hacc[ct];
    }
    __syncthreads();
    if (tid < 128) {
        float s = (red[tid] + red[128 + tid]) + (red[256 + tid] + red[384 + tid]);
        atomicAdd(&hsum[tid], s);
    }
}

__global__ void k_out(const float* __restrict__ hsum, const float* __restrict__ W2,
                      const float* __restrict__ b2, float* __restrict__ out) {
    int j = threadIdx.x;
    if (j < 3) {
        float acc = 0.0f;
        for (int k = 0; k < DD; ++k) acc += hsum[k] * W2[j * DD + k];
        out[j] = acc + (float)NN * b2[j];
    }
}

extern "C" void kernel_launch(void* const* d_in, const int* in_sizes, int n_in,
                              void* d_out, int out_size, void* d_ws, size_t ws_size,
                              hipStream_t stream) {
    const float* x  = (const float*)d_in[0];
    const int* ei   = (const int*)d_in[1];
    const float* Wl = (const float*)d_in[2];
    const float* bl = (const float*)d_in[3];
    const float* W1 = (const float*)d_in[4];
    const float* b1 = (const float*)d_in[5];
    const float* W2 = (const float*)d_in[6];
    const float* b2 = (const float*)d_in[7];

    // ws layout (~19.5 MB): xb[NN*DD bf16] | hsum[DD f32] | cnt[NN int] | slot[NN*64 ushort] | wbl | wb1
    char* wsb     = (char*)d_ws;
    ushort* xb    = (ushort*)wsb;                              // 12,800,000 B
    float* hsum   = (float*)(xb + (size_t)NN * DD);            // +512 B
    int* cnt      = (int*)(hsum + DD);                         // +200,000 B
    ushort* slot  = (ushort*)(cnt + NN);                       // +6,400,000 B
    ushort* wbl   = slot + (size_t)NN * SLOTS;                 // +32,768 B
    ushort* wb1   = wbl + DD * DD;                             // +32,768 B

    k_init<<<(NN * 32 + 255) / 256, 256, 0, stream>>>((const float4*)x, (uint2*)xb,
                                                      (const float4*)Wl, (const float4*)W1,
                                                      (uint2*)wbl, (uint2*)wb1, cnt, hsum);
    k_scatter<<<(NE + 255) / 256, 256, 0, stream>>>(ei, cnt, slot);

    int nblk = (NN / 16 + 3) / 4;   // 782: one 16-node tile per wave
    k_fused<<<nblk, 256, 0, stream>>>((const uint4*)xb, cnt, slot, wbl, wb1, bl, b1, hsum);

    k_out<<<1, 64, 0, stream>>>(hsum, W2, b2, (float*)d_out);
}

// Round 7
// 117.756 us; speedup vs baseline: 1.3450x; 1.3450x over previous
//
#include <hip/hip_runtime.h>

#define NN 50000
#define NE 600000
#define DD 128
#define SLOTS 64   // deg ~ Poisson(12); P(deg>=64) ~ 1e-31 -> safe fixed-capacity buckets

typedef float f32x4 __attribute__((ext_vector_type(4)));
typedef short bf16x8 __attribute__((ext_vector_type(8)));

__device__ __forceinline__ ushort f2bf(float f) {           // RNE f32 -> bf16
    uint u = __float_as_uint(f);
    u = (u + 0x7FFFu + ((u >> 16) & 1u)) >> 16;
    return (ushort)u;
}
__device__ __forceinline__ float bfhi2f(uint u) { return __uint_as_float(u & 0xFFFF0000u); }
__device__ __forceinline__ float bflo2f(uint u) { return __uint_as_float(u << 16); }

// ---------------- init: cast x and weights to bf16, zero cnt/hsum ----------------

__global__ void k_init(const float4* __restrict__ x4, uint2* __restrict__ xb,
                       const float4* __restrict__ Wl4, const float4* __restrict__ W14,
                       uint2* __restrict__ wbl2, uint2* __restrict__ wb12,
                       int* __restrict__ cnt, float* __restrict__ hsum) {
    int i = blockIdx.x * blockDim.x + threadIdx.x;
    if (i < NN * 32) {
        float4 v = x4[i];
        uint2 o;
        o.x = (uint)f2bf(v.x) | ((uint)f2bf(v.y) << 16);
        o.y = (uint)f2bf(v.z) | ((uint)f2bf(v.w) << 16);
        xb[i] = o;
    }
    if (i < 4096) {   // 16384 f32 per weight
        float4 v = Wl4[i];
        uint2 o;
        o.x = (uint)f2bf(v.x) | ((uint)f2bf(v.y) << 16);
        o.y = (uint)f2bf(v.z) | ((uint)f2bf(v.w) << 16);
        wbl2[i] = o;
        v = W14[i];
        o.x = (uint)f2bf(v.x) | ((uint)f2bf(v.y) << 16);
        o.y = (uint)f2bf(v.z) | ((uint)f2bf(v.w) << 16);
        wb12[i] = o;
    }
    if (i < NN) cnt[i] = 0;
    if (i < DD) hsum[i] = 0.0f;
}

// ---------------- bucket scatter: slot[dst*64 + pos] = src (ushort) ----------------

__global__ void k_scatter(const int* __restrict__ ei, int* __restrict__ cnt, ushort* __restrict__ slot) {
    int e = blockIdx.x * blockDim.x + threadIdx.x;
    if (e < NE) {
        int dst = ei[NE + e];
        int pos = atomicAdd(&cnt[dst], 1);
        slot[(size_t)dst * SLOTS + pos] = (ushort)ei[e];
    }
}

// ---------------- gather: half-wave (32 lanes x uint2) per node, high occupancy ----------------

__global__ __launch_bounds__(256) void k_gather(const uint2* __restrict__ xb2,
                                                const int* __restrict__ cnt,
                                                const ushort* __restrict__ slot,
                                                uint2* __restrict__ meanb2) {
    int gt = blockIdx.x * blockDim.x + threadIdx.x;
    int wid = gt >> 5;          // node
    int lane = gt & 31;         // 4 features per lane
    if (wid >= NN) return;
    uint2 s = xb2[(size_t)wid * 32 + lane];   // self loop
    float a0 = bflo2f(s.x), a1 = bfhi2f(s.x), a2 = bflo2f(s.y), a3 = bfhi2f(s.y);
    const ushort* sl = slot + (size_t)wid * SLOTS;
    int n = cnt[wid];
    int j = 0;
    for (; j + 3 < n; j += 4) {
        int s0 = sl[j], s1 = sl[j + 1], s2 = sl[j + 2], s3 = sl[j + 3];
        uint2 v0 = xb2[(size_t)s0 * 32 + lane];
        uint2 v1 = xb2[(size_t)s1 * 32 + lane];
        uint2 v2 = xb2[(size_t)s2 * 32 + lane];
        uint2 v3 = xb2[(size_t)s3 * 32 + lane];
        a0 += bflo2f(v0.x) + bflo2f(v1.x) + bflo2f(v2.x) + bflo2f(v3.x);
        a1 += bfhi2f(v0.x) + bfhi2f(v1.x) + bfhi2f(v2.x) + bfhi2f(v3.x);
        a2 += bflo2f(v0.y) + bflo2f(v1.y) + bflo2f(v2.y) + bflo2f(v3.y);
        a3 += bfhi2f(v0.y) + bfhi2f(v1.y) + bfhi2f(v2.y) + bfhi2f(v3.y);
    }
    for (; j < n; ++j) {
        uint2 v = xb2[(size_t)sl[j] * 32 + lane];
        a0 += bflo2f(v.x); a1 += bfhi2f(v.x);
        a2 += bflo2f(v.y); a3 += bfhi2f(v.y);
    }
    float rc = 1.0f / (float)(n + 1);
    uint2 o;
    o.x = (uint)f2bf(a0 * rc) | ((uint)f2bf(a1 * rc) << 16);
    o.y = (uint)f2bf(a2 * rc) | ((uint)f2bf(a3 * rc) << 16);
    meanb2[(size_t)wid * 32 + lane] = o;
}

// ---------------- MFMA MLP tail: agg=mean@Wl^T+bl ; h=relu(agg@W1^T+b1) ; hsum+=col-sum ----------------
// Wave-tile = 16 nodes, one tile per wave (grid 782x4 waves >= 3125 tiles).
// A-frags direct from global meanb; B-frags direct from global bf16 weights (64 KB, L2-hot).
// LDS only for the per-wave layer1->layer2 transpose bounce (16 KB).
// MFMA 16x16x32 bf16: A[m=l&15][k=(l>>4)*8+j]; C col=l&15, row=(l>>4)*4+reg.

__global__ __launch_bounds__(256) void k_fused(const ushort* __restrict__ meanb,
                                               const ushort* __restrict__ wbl,
                                               const ushort* __restrict__ wb1,
                                               const float* __restrict__ bl,
                                               const float* __restrict__ b1,
                                               float* __restrict__ hsum) {
    __shared__ ushort sAgg[4 * 2048];   // 16 KB

    int tid = threadIdx.x;
    int wid = tid >> 6, lane = tid & 63;
    int lm = lane & 15, lq = lane >> 4;

    float blr[8], b1r[8], hacc[8];
    #pragma unroll
    for (int ct = 0; ct < 8; ++ct) {
        blr[ct] = bl[ct * 16 + lm];
        b1r[ct] = b1[ct * 16 + lm];
        hacc[ct] = 0.0f;
    }

    ushort* myAgg = &sAgg[wid * 2048];
    const int NT = NN / 16;   // 3125

    for (int wt = blockIdx.x * 4 + wid; wt < NT; wt += gridDim.x * 4) {
        int nbase = wt * 16;

        // ---- layer 1: agg = mean @ Wl^T + bl ----
        bf16x8 afr[4];
        #pragma unroll
        for (int kt = 0; kt < 4; ++kt)
            afr[kt] = *(const bf16x8*)&meanb[(size_t)(nbase + lm) * 128 + kt * 32 + lq * 8];

        #pragma unroll
        for (int ct = 0; ct < 8; ++ct) {
            f32x4 acc = {0.f, 0.f, 0.f, 0.f};
            int rB = ct * 16 + lm;
            #pragma unroll
            for (int kt = 0; kt < 4; ++kt) {
                bf16x8 bfr = *(const bf16x8*)&wbl[rB * 128 + (kt * 4 + lq) * 8];
                acc = __builtin_amdgcn_mfma_f32_16x16x32_bf16(afr[kt], bfr, acc, 0, 0, 0);
            }
            #pragma unroll
            for (int r = 0; r < 4; ++r) {
                int n = lq * 4 + r;
                int col = ct * 16 + lm;
                myAgg[n * 128 + (((col >> 3) ^ (n & 7)) << 3) + (col & 7)] = f2bf(acc[r] + blr[ct]);
            }
        }

        // ---- layer 2: h = relu(agg @ W1^T + b1), accumulate column sums ----
        bf16x8 afr2[4];
        #pragma unroll
        for (int kt = 0; kt < 4; ++kt)
            afr2[kt] = *(const bf16x8*)&myAgg[lm * 128 + (((kt * 4 + lq) ^ (lm & 7)) << 3)];

        #pragma unroll
        for (int ct = 0; ct < 8; ++ct) {
            f32x4 acc = {0.f, 0.f, 0.f, 0.f};
            int rB = ct * 16 + lm;
            #pragma unroll
            for (int kt = 0; kt < 4; ++kt) {
                bf16x8 bfr = *(const bf16x8*)&wb1[rB * 128 + (kt * 4 + lq) * 8];
                acc = __builtin_amdgcn_mfma_f32_16x16x32_bf16(afr2[kt], bfr, acc, 0, 0, 0);
            }
            float s0 = fmaxf(acc[0] + b1r[ct], 0.f);
            float s1 = fmaxf(acc[1] + b1r[ct], 0.f);
            float s2 = fmaxf(acc[2] + b1r[ct], 0.f);
            float s3 = fmaxf(acc[3] + b1r[ct], 0.f);
            hacc[ct] += (s0 + s1) + (s2 + s3);
        }
    }

    // reduce: lanes sharing lm hold disjoint node subsets
    #pragma unroll
    for (int ct = 0; ct < 8; ++ct) {
        float v = hacc[ct];
        v += __shfl_xor(v, 16);
        v += __shfl_xor(v, 32);
        hacc[ct] = v;
    }
    __syncthreads();
    float* red = (float*)sAgg;
    if (lane < 16) {
        #pragma unroll
        for (int ct = 0; ct < 8; ++ct) red[wid * 128 + ct * 16 + lane] = hacc[ct];
    }
    __syncthreads();
    if (tid < 128) {
        float s = (red[tid] + red[128 + tid]) + (red[256 + tid] + red[384 + tid]);
        atomicAdd(&hsum[tid], s);
    }
}

__global__ void k_out(const float* __restrict__ hsum, const float* __restrict__ W2,
                      const float* __restrict__ b2, float* __restrict__ out) {
    int j = threadIdx.x;
    if (j < 3) {
        float acc = 0.0f;
        for (int k = 0; k < DD; ++k) acc += hsum[k] * W2[j * DD + k];
        out[j] = acc + (float)NN * b2[j];
    }
}

extern "C" void kernel_launch(void* const* d_in, const int* in_sizes, int n_in,
                              void* d_out, int out_size, void* d_ws, size_t ws_size,
                              hipStream_t stream) {
    const float* x  = (const float*)d_in[0];
    const int* ei   = (const int*)d_in[1];
    const float* Wl = (const float*)d_in[2];
    const float* bl = (const float*)d_in[3];
    const float* W1 = (const float*)d_in[4];
    const float* b1 = (const float*)d_in[5];
    const float* W2 = (const float*)d_in[6];
    const float* b2 = (const float*)d_in[7];

    // ws layout (~32 MB): xb | meanb | hsum | cnt | slot(ushort) | wbl | wb1
    char* wsb     = (char*)d_ws;
    ushort* xb    = (ushort*)wsb;                              // NN*DD bf16
    ushort* meanb = xb + (size_t)NN * DD;                      // NN*DD bf16
    float* hsum   = (float*)(meanb + (size_t)NN * DD);         // DD f32
    int* cnt      = (int*)(hsum + DD);                         // NN int
    ushort* slot  = (ushort*)(cnt + NN);                       // NN*64 ushort
    ushort* wbl   = slot + (size_t)NN * SLOTS;                 // DD*DD bf16
    ushort* wb1   = wbl + DD * DD;                             // DD*DD bf16

    k_init<<<(NN * 32 + 255) / 256, 256, 0, stream>>>((const float4*)x, (uint2*)xb,
                                                      (const float4*)Wl, (const float4*)W1,
                                                      (uint2*)wbl, (uint2*)wb1, cnt, hsum);
    k_scatter<<<(NE + 255) / 256, 256, 0, stream>>>(ei, cnt, slot);
    k_gather<<<(NN * 32 + 255) / 256, 256, 0, stream>>>((const uint2*)xb, cnt, slot, (uint2*)meanb);

    int nblk = (NN / 16 + 3) / 4;   // 782: one 16-node tile per wave
    k_fused<<<nblk, 256, 0, stream>>>(meanb, wbl, wb1, bl, b1, hsum);

    k_out<<<1, 64, 0, stream>>>(hsum, W2, b2, (float*)d_out);
}

// Round 8
// 92.858 us; speedup vs baseline: 1.7056x; 1.2681x over previous
//
#include <hip/hip_runtime.h>

#define NN 50000
#define NE 600000
#define DD 128
#define SLOTS 64   // deg ~ Poisson(12); P(deg>=64) ~ 1e-31 -> safe fixed-capacity buckets

typedef float f32x4 __attribute__((ext_vector_type(4)));
typedef short bf16x8 __attribute__((ext_vector_type(8)));

__device__ __forceinline__ ushort f2bf(float f) {           // RNE f32 -> bf16
    uint u = __float_as_uint(f);
    u = (u + 0x7FFFu + ((u >> 16) & 1u)) >> 16;
    return (ushort)u;
}
__device__ __forceinline__ float bfhi2f(uint u) { return __uint_as_float(u & 0xFFFF0000u); }
__device__ __forceinline__ float bflo2f(uint u) { return __uint_as_float(u << 16); }

// ---------------- init: cast x and weights to bf16, zero cnt/hsum ----------------

__global__ void k_init(const float4* __restrict__ x4, uint2* __restrict__ xb,
                       const float4* __restrict__ Wl4, const float4* __restrict__ W14,
                       uint2* __restrict__ wbl2, uint2* __restrict__ wb12,
                       int* __restrict__ cnt, float* __restrict__ hsum) {
    int i = blockIdx.x * blockDim.x + threadIdx.x;
    if (i < NN * 32) {
        float4 v = x4[i];
        uint2 o;
        o.x = (uint)f2bf(v.x) | ((uint)f2bf(v.y) << 16);
        o.y = (uint)f2bf(v.z) | ((uint)f2bf(v.w) << 16);
        xb[i] = o;
    }
    if (i < 4096) {   // 16384 f32 per weight
        float4 v = Wl4[i];
        uint2 o;
        o.x = (uint)f2bf(v.x) | ((uint)f2bf(v.y) << 16);
        o.y = (uint)f2bf(v.z) | ((uint)f2bf(v.w) << 16);
        wbl2[i] = o;
        v = W14[i];
        o.x = (uint)f2bf(v.x) | ((uint)f2bf(v.y) << 16);
        o.y = (uint)f2bf(v.z) | ((uint)f2bf(v.w) << 16);
        wb12[i] = o;
    }
    if (i < NN) cnt[i] = 0;
    if (i < DD) hsum[i] = 0.0f;
}

// ---------------- bucket scatter: slot[dst*64 + pos] = src (ushort) ----------------

__global__ void k_scatter(const int* __restrict__ ei, int* __restrict__ cnt, ushort* __restrict__ slot) {
    int e = blockIdx.x * blockDim.x + threadIdx.x;
    if (e < NE) {
        int dst = ei[NE + e];
        int pos = atomicAdd(&cnt[dst], 1);
        slot[(size_t)dst * SLOTS + pos] = (ushort)ei[e];
    }
}

// ---------------- gather: 16 lanes x uint4 per node -> 4 nodes/wave, 16 loads in flight ----------------

__global__ __launch_bounds__(256) void k_gather(const uint4* __restrict__ xb4,
                                                const int* __restrict__ cnt,
                                                const ushort* __restrict__ slot,
                                                uint4* __restrict__ meanb4) {
    int gt = blockIdx.x * blockDim.x + threadIdx.x;
    int wid = gt >> 4;          // node
    int lane = gt & 15;         // 8 features per lane (uint4 = 4x2 bf16)
    if (wid >= NN) return;
    uint4 s = xb4[(size_t)wid * 16 + lane];   // self loop
    float a0 = bflo2f(s.x), a1 = bfhi2f(s.x), a2 = bflo2f(s.y), a3 = bfhi2f(s.y);
    float a4 = bflo2f(s.z), a5 = bfhi2f(s.z), a6 = bflo2f(s.w), a7 = bfhi2f(s.w);
    const ushort* sl = slot + (size_t)wid * SLOTS;
    int n = cnt[wid];
    int j = 0;
    for (; j + 3 < n; j += 4) {
        int s0 = sl[j], s1 = sl[j + 1], s2 = sl[j + 2], s3 = sl[j + 3];
        uint4 v0 = xb4[(size_t)s0 * 16 + lane];
        uint4 v1 = xb4[(size_t)s1 * 16 + lane];
        uint4 v2 = xb4[(size_t)s2 * 16 + lane];
        uint4 v3 = xb4[(size_t)s3 * 16 + lane];
        a0 += bflo2f(v0.x) + bflo2f(v1.x) + bflo2f(v2.x) + bflo2f(v3.x);
        a1 += bfhi2f(v0.x) + bfhi2f(v1.x) + bfhi2f(v2.x) + bfhi2f(v3.x);
        a2 += bflo2f(v0.y) + bflo2f(v1.y) + bflo2f(v2.y) + bflo2f(v3.y);
        a3 += bfhi2f(v0.y) + bfhi2f(v1.y) + bfhi2f(v2.y) + bfhi2f(v3.y);
        a4 += bflo2f(v0.z) + bflo2f(v1.z) + bflo2f(v2.z) + bflo2f(v3.z);
        a5 += bfhi2f(v0.z) + bfhi2f(v1.z) + bfhi2f(v2.z) + bfhi2f(v3.z);
        a6 += bflo2f(v0.w) + bflo2f(v1.w) + bflo2f(v2.w) + bflo2f(v3.w);
        a7 += bfhi2f(v0.w) + bfhi2f(v1.w) + bfhi2f(v2.w) + bfhi2f(v3.w);
    }
    for (; j < n; ++j) {
        uint4 v = xb4[(size_t)sl[j] * 16 + lane];
        a0 += bflo2f(v.x); a1 += bfhi2f(v.x);
        a2 += bflo2f(v.y); a3 += bfhi2f(v.y);
        a4 += bflo2f(v.z); a5 += bfhi2f(v.z);
        a6 += bflo2f(v.w); a7 += bfhi2f(v.w);
    }
    float rc = 1.0f / (float)(n + 1);
    uint4 o;
    o.x = (uint)f2bf(a0 * rc) | ((uint)f2bf(a1 * rc) << 16);
    o.y = (uint)f2bf(a2 * rc) | ((uint)f2bf(a3 * rc) << 16);
    o.z = (uint)f2bf(a4 * rc) | ((uint)f2bf(a5 * rc) << 16);
    o.w = (uint)f2bf(a6 * rc) | ((uint)f2bf(a7 * rc) << 16);
    meanb4[(size_t)wid * 16 + lane] = o;
}

// ---------------- MFMA MLP tail (round-5 structure, bf16 LDS-staged weights) ----------------

__global__ __launch_bounds__(256) void k_fused(const ushort* __restrict__ meanb,
                                               const uint4* __restrict__ wbl4,
                                               const uint4* __restrict__ wb14,
                                               const float* __restrict__ bl,
                                               const float* __restrict__ b1,
                                               float* __restrict__ hsum) {
    __shared__ ushort sWl[128 * 128];   // 32 KB bf16
    __shared__ ushort sW1[128 * 128];   // 32 KB bf16
    __shared__ ushort sAgg[4 * 2048];   // 16 KB

    int tid = threadIdx.x;
    int wid = tid >> 6, lane = tid & 63;
    int lm = lane & 15, lq = lane >> 4;

    for (int idx = tid; idx < 2048; idx += 256) {   // 128 rows x 16 granules (16 B bf16 each)
        int r = idx >> 4, g = idx & 15;
        int dst = r * 128 + ((g ^ (r & 7)) << 3);
        *(uint4*)&sWl[dst] = wbl4[idx];
        *(uint4*)&sW1[dst] = wb14[idx];
    }
    __syncthreads();

    float blr[8], b1r[8], hacc[8];
    #pragma unroll
    for (int ct = 0; ct < 8; ++ct) {
        blr[ct] = bl[ct * 16 + lm];
        b1r[ct] = b1[ct * 16 + lm];
        hacc[ct] = 0.0f;
    }

    ushort* myAgg = &sAgg[wid * 2048];
    const int NT = NN / 16;   // 3125

    for (int wt = blockIdx.x * 4 + wid; wt < NT; wt += gridDim.x * 4) {
        int nbase = wt * 16;

        bf16x8 afr[4];
        #pragma unroll
        for (int kt = 0; kt < 4; ++kt)
            afr[kt] = *(const bf16x8*)&meanb[(size_t)(nbase + lm) * 128 + kt * 32 + lq * 8];

        #pragma unroll
        for (int ct = 0; ct < 8; ++ct) {
            f32x4 acc = {0.f, 0.f, 0.f, 0.f};
            int rB = ct * 16 + lm;
            #pragma unroll
            for (int kt = 0; kt < 4; ++kt) {
                bf16x8 bfr = *(const bf16x8*)&sWl[rB * 128 + (((kt * 4 + lq) ^ (rB & 7)) << 3)];
                acc = __builtin_amdgcn_mfma_f32_16x16x32_bf16(afr[kt], bfr, acc, 0, 0, 0);
            }
            #pragma unroll
            for (int r = 0; r < 4; ++r) {
                int n = lq * 4 + r;
                int col = ct * 16 + lm;
                myAgg[n * 128 + (((col >> 3) ^ (n & 7)) << 3) + (col & 7)] = f2bf(acc[r] + blr[ct]);
            }
        }

        bf16x8 afr2[4];
        #pragma unroll
        for (int kt = 0; kt < 4; ++kt)
            afr2[kt] = *(const bf16x8*)&myAgg[lm * 128 + (((kt * 4 + lq) ^ (lm & 7)) << 3)];

        #pragma unroll
        for (int ct = 0; ct < 8; ++ct) {
            f32x4 acc = {0.f, 0.f, 0.f, 0.f};
            int rB = ct * 16 + lm;
            #pragma unroll
            for (int kt = 0; kt < 4; ++kt) {
                bf16x8 bfr = *(const bf16x8*)&sW1[rB * 128 + (((kt * 4 + lq) ^ (rB & 7)) << 3)];
                acc = __builtin_amdgcn_mfma_f32_16x16x32_bf16(afr2[kt], bfr, acc, 0, 0, 0);
            }
            float s0 = fmaxf(acc[0] + b1r[ct], 0.f);
            float s1 = fmaxf(acc[1] + b1r[ct], 0.f);
            float s2 = fmaxf(acc[2] + b1r[ct], 0.f);
            float s3 = fmaxf(acc[3] + b1r[ct], 0.f);
            hacc[ct] += (s0 + s1) + (s2 + s3);
        }
    }

    #pragma unroll
    for (int ct = 0; ct < 8; ++ct) {
        float v = hacc[ct];
        v += __shfl_xor(v, 16);
        v += __shfl_xor(v, 32);
        hacc[ct] = v;
    }
    __syncthreads();
    float* red = (float*)sAgg;
    if (lane < 16) {
        #pragma unroll
        for (int ct = 0; ct < 8; ++ct) red[wid * 128 + ct * 16 + lane] = hacc[ct];
    }
    __syncthreads();
    if (tid < 128) {
        float s = (red[tid] + red[128 + tid]) + (red[256 + tid] + red[384 + tid]);
        atomicAdd(&hsum[tid], s);
    }
}

__global__ void k_out(const float* __restrict__ hsum, const float* __restrict__ W2,
                      const float* __restrict__ b2, float* __restrict__ out) {
    int j = threadIdx.x;
    if (j < 3) {
        float acc = 0.0f;
        for (int k = 0; k < DD; ++k) acc += hsum[k] * W2[j * DD + k];
        out[j] = acc + (float)NN * b2[j];
    }
}

extern "C" void kernel_launch(void* const* d_in, const int* in_sizes, int n_in,
                              void* d_out, int out_size, void* d_ws, size_t ws_size,
                              hipStream_t stream) {
    const float* x  = (const float*)d_in[0];
    const int* ei   = (const int*)d_in[1];
    const float* Wl = (const float*)d_in[2];
    const float* bl = (const float*)d_in[3];
    const float* W1 = (const float*)d_in[4];
    const float* b1 = (const float*)d_in[5];
    const float* W2 = (const float*)d_in[6];
    const float* b2 = (const float*)d_in[7];

    // ws layout (~32 MB): xb | meanb | hsum | cnt | slot(ushort) | wbl | wb1
    char* wsb     = (char*)d_ws;
    ushort* xb    = (ushort*)wsb;                              // NN*DD bf16
    ushort* meanb = xb + (size_t)NN * DD;                      // NN*DD bf16
    float* hsum   = (float*)(meanb + (size_t)NN * DD);         // DD f32
    int* cnt      = (int*)(hsum + DD);                         // NN int
    ushort* slot  = (ushort*)(cnt + NN);                       // NN*64 ushort
    ushort* wbl   = slot + (size_t)NN * SLOTS;                 // DD*DD bf16
    ushort* wb1   = wbl + DD * DD;                             // DD*DD bf16

    k_init<<<(NN * 32 + 255) / 256, 256, 0, stream>>>((const float4*)x, (uint2*)xb,
                                                      (const float4*)Wl, (const float4*)W1,
                                                      (uint2*)wbl, (uint2*)wb1, cnt, hsum);
    k_scatter<<<(NE + 255) / 256, 256, 0, stream>>>(ei, cnt, slot);
    k_gather<<<(NN * 16 + 255) / 256, 256, 0, stream>>>((const uint4*)xb, cnt, slot, (uint4*)meanb);
    k_fused<<<512, 256, 0, stream>>>(meanb, (const uint4*)wbl, (const uint4*)wb1, bl, b1, hsum);
    k_out<<<1, 64, 0, stream>>>(hsum, W2, b2, (float*)d_out);
}